// Round 5
// baseline (784.260 us; speedup 1.0000x reference)
//
#include <hip/hip_runtime.h>
#include <hip/hip_bf16.h>

// ---------------- param layout inside ws (floats) ----------------
#define P_W1  0
#define P_AS1 16384
#define P_AD1 16448
#define P_B1  16512
#define P_W2  16576
#define P_AS2 16768
#define P_AD2 16771
#define P_B2  16774

typedef __attribute__((ext_vector_type(8))) short short8;
typedef __attribute__((ext_vector_type(4))) float floatx4;

// runtime-dtype load helpers
__device__ __forceinline__ float ldf(const void* p, int i, int bf) {
  if (bf) {
    unsigned v = ((unsigned)((const unsigned short*)p)[i]) << 16;
    float f; __builtin_memcpy(&f, &v, 4); return f;
  }
  return ((const float*)p)[i];
}
__device__ __forceinline__ int ldi(const void* p, long i, int i64) {
  return i64 ? ((const int*)p)[2*i] : ((const int*)p)[i];
}
__device__ __forceinline__ unsigned short f2bfbits(float f) {
  __hip_bfloat16 b = __float2bfloat16(f);
  unsigned short u; __builtin_memcpy(&u, &b, 2); return u;
}

// ---------------- K0: dtype detection + param conversion ----------------
__global__ void k_prep(const void* x, const void* ei,
                       const void* w1, const void* as1, const void* ad1, const void* b1,
                       const void* w2, const void* as2, const void* ad2, const void* b2,
                       int* flags, float* params, unsigned short* w1t) {
  __shared__ int sh[2];
  int tid = threadIdx.x, lane = tid & 63, w = tid >> 6;
  if (w == 0) {
    const unsigned* xw = (const unsigned*)x;
    int hits = 0;
    for (int i = lane; i < 256; i += 64) {
      unsigned b = (xw[i] >> 7) & 0xFF;
      hits += (b >= 96 && b <= 141) ? 1 : 0;
    }
    for (int o = 32; o >= 1; o >>= 1) hits += __shfl_xor(hits, o);
    if (lane == 0) sh[0] = (hits >= 160) ? 1 : 0;
  } else if (w == 1) {
    const unsigned* ew = (const unsigned*)ei;
    int z = 0;
    for (int i = lane; i < 128; i += 64) z += (ew[2*i+1] == 0u) ? 1 : 0;
    for (int o = 32; o >= 1; o >>= 1) z += __shfl_xor(z, o);
    if (lane == 0) sh[1] = (z >= 64) ? 1 : 0;
  }
  __syncthreads();
  int bf = sh[0];
  if (tid == 0) { flags[0] = sh[0]; flags[1] = sh[1]; }
  for (int i = tid; i < 16384; i += blockDim.x) {
    int ch = i >> 8, k = i & 255;
    w1t[i] = f2bfbits(ldf(w1, k * 64 + ch, bf));
  }
  if (!bf) {
    for (int i = tid; i < 16384; i += blockDim.x) params[P_W1 + i] = ldf(w1, i, bf);
  }
  for (int i = tid; i < 64; i += blockDim.x) {
    params[P_AS1 + i] = ldf(as1, i, bf);
    params[P_AD1 + i] = ldf(ad1, i, bf);
    params[P_B1  + i] = ldf(b1,  i, bf);
  }
  for (int i = tid; i < 192; i += blockDim.x) params[P_W2 + i] = ldf(w2, i, bf);
  for (int i = tid; i < 3; i += blockDim.x) {
    params[P_AS2 + i] = ldf(as2, i, bf);
    params[P_AD2 + i] = ldf(ad2, i, bf);
    params[P_B2  + i] = ldf(b2,  i, bf);
  }
}

// ---------------- K1: h1 = x @ W1 via MFMA, W-stationary in LDS, operand-swapped ----------------
// block = 256 thr = 4 waves = 64 nodes. A = W (m=ch), B = x (n=node) so each lane's
// 4 acc regs are 4 consecutive channels of ONE node -> dwordx4 h1 stores.
#define WPAD 264   // W LDS row pitch (bf16): min-phase b128 reads verified
#define XPAD 272   // x LDS row pitch

__device__ __forceinline__ void gemm1_f32(const float* x, const float* params,
                                          float* h1, float* a_s, float* a_d,
                                          int N, int wave, int lane) {
  int n0 = wave * 4;
  if (n0 >= N) return;
  int nb[4];
#pragma unroll
  for (int j = 0; j < 4; j++) nb[j] = min(n0 + j, N - 1) * 256;
  float acc[4] = {0.f, 0.f, 0.f, 0.f};
  const float* W = params + P_W1;
  for (int k = 0; k < 256; k++) {
    float wv = W[k * 64 + lane];
#pragma unroll
    for (int j = 0; j < 4; j++) acc[j] += x[nb[j] + k] * wv;
  }
  float as1v = params[P_AS1 + lane], ad1v = params[P_AD1 + lane];
#pragma unroll
  for (int j = 0; j < 4; j++) {
    int n = n0 + j;
    if (n >= N) break;
    float hv = acc[j];
    float s = hv * as1v, d = hv * ad1v;
    s += __shfl_xor(s, 1); s += __shfl_xor(s, 2); s += __shfl_xor(s, 4);
    d += __shfl_xor(d, 1); d += __shfl_xor(d, 2); d += __shfl_xor(d, 4);
    h1[(size_t)n * 64 + lane] = hv;
    if ((lane & 7) == 0) {
      a_s[n * 8 + (lane >> 3)] = s;
      a_d[n * 8 + (lane >> 3)] = d;
    }
  }
}

__global__ void __launch_bounds__(256, 2)
k_gemm1(const void* x, const unsigned short* w1t, const int* flags,
        const float* params, float* h1, float* a_s, float* a_d, int N) {
  __shared__ unsigned short ws_w[64 * WPAD];  // 33,792 B
  __shared__ unsigned short xs[64 * XPAD];    // 34,816 B
  __shared__ float as_t[512], ad_t[512];      // 4 KB
  int tid = threadIdx.x;
  int w = tid >> 6, lane = tid & 63;
  if (flags[0]) {
    const unsigned short* xb = (const unsigned short*)x;
    int n0 = blockIdx.x * 64;
    // stage W1t (32 KB) and x tile (32 KB), both fully coalesced dwordx4
#pragma unroll
    for (int j = 0; j < 8; j++) {
      int c = tid + j * 256;               // dwordx4 chunk id (2048 per array)
      int r = c >> 5, col = c & 31;        // 32 chunks per 512B row
      uint4 wv4 = *(const uint4*)(w1t + (size_t)r * 256 + col * 8);
      *(uint4*)(ws_w + r * WPAD + col * 8) = wv4;
      int gn = n0 + r; if (gn >= N) gn = N - 1;
      uint4 xv4 = *(const uint4*)(xb + (size_t)gn * 256 + col * 8);
      *(uint4*)(xs + r * XPAD + col * 8) = xv4;
    }
    __syncthreads();
    int quad = lane >> 4, l16 = lane & 15;
    floatx4 acc[4] = {{0,0,0,0},{0,0,0,0},{0,0,0,0},{0,0,0,0}};
    const unsigned short* xrow = xs + (w * 16 + l16) * XPAD + quad * 8;
    const unsigned short* wr0 = ws_w + l16 * WPAD + quad * 8;
#pragma unroll
    for (int k0 = 0; k0 < 256; k0 += 32) {
      short8 bx = *(const short8*)(xrow + k0);
#pragma unroll
      for (int ct = 0; ct < 4; ct++) {
        short8 aw = *(const short8*)(wr0 + ct * 16 * WPAD + k0);
        acc[ct] = __builtin_amdgcn_mfma_f32_16x16x32_bf16(aw, bx, acc[ct], 0, 0, 0);
      }
    }
    int n = n0 + w * 16 + l16;            // D: col=l16 -> node, row=quad*4+r -> ch
    bool nv = n < N;
#pragma unroll
    for (int ct = 0; ct < 4; ct++) {
      int chb = ct * 16 + quad * 4;
      float4 dv = make_float4(acc[ct][0], acc[ct][1], acc[ct][2], acc[ct][3]);
      if (nv) *(float4*)(h1 + (size_t)n * 64 + chb) = dv;
      float sp = dv.x * params[P_AS1+chb] + dv.y * params[P_AS1+chb+1]
               + dv.z * params[P_AS1+chb+2] + dv.w * params[P_AS1+chb+3];
      float dp = dv.x * params[P_AD1+chb] + dv.y * params[P_AD1+chb+1]
               + dv.z * params[P_AD1+chb+2] + dv.w * params[P_AD1+chb+3];
      sp += __shfl_xor(sp, 16);           // combine quad pairs (same head)
      dp += __shfl_xor(dp, 16);
      if ((quad & 1) == 0) {
        int head = ct * 2 + (quad >> 1);
        as_t[(w * 16 + l16) * 8 + head] = sp;
        ad_t[(w * 16 + l16) * 8 + head] = dp;
      }
    }
    __syncthreads();
    // coalesced alpha flush
    for (int t = tid; t < 512; t += 256) {
      int n2 = n0 + (t >> 3);
      if (n2 < N) { a_s[n0 * 8 + t] = as_t[t]; a_d[n0 * 8 + t] = ad_t[t]; }
    }
  } else {
#pragma unroll
    for (int j = 0; j < 4; j++)
      gemm1_f32((const float*)x, params, h1, a_s, a_d, N,
                blockIdx.x * 16 + j * 4 + w, lane);
  }
}

// ---------------- CSR build: 2-level bucket sort (bucket = dst >> 9) ----------------
__global__ void k_bcount(const void* ei, const int* flags, int* gcnt, int* brsv,
                         int E0, int N, int NB, int chunk) {
  __shared__ int h[256];
  int i64 = flags[1], tid = threadIdx.x;
  for (int j = tid; j < NB; j += 256) h[j] = 0;
  __syncthreads();
  int E = E0 + N;
  int b0 = blockIdx.x * chunk, b1 = min(b0 + chunk, E);
  for (int e = b0 + tid; e < b1; e += 256) {
    int dst = (e < E0) ? ldi(ei, (long)E0 + e, i64) : (e - E0);
    atomicAdd(&h[dst >> 9], 1);
  }
  __syncthreads();
  for (int j = tid; j < NB; j += 256)
    brsv[blockIdx.x * NB + j] = atomicAdd(&gcnt[j], h[j]);
}

__global__ void k_bbase(const int* gcnt, int* bbase, int NB) {
  __shared__ int sh[256];
  int tid = threadIdx.x;
  sh[tid] = (tid < NB) ? gcnt[tid] : 0;
  __syncthreads();
  int own = sh[tid];
  for (int ofs = 1; ofs < 256; ofs <<= 1) {
    int v = (tid >= ofs) ? sh[tid - ofs] : 0;
    __syncthreads();
    sh[tid] += v;
    __syncthreads();
  }
  if (tid < NB) bbase[tid] = sh[tid] - own;
  if (tid == NB - 1) bbase[NB] = sh[tid];
}

__global__ void k_bscatter(const void* ei, const int* flags, const int* bbase,
                           const int* brsv, unsigned* pairs, int E0, int N, int NB, int chunk) {
  __shared__ int base_s[256];
  __shared__ int rnk[256];
  int i64 = flags[1], tid = threadIdx.x;
  for (int j = tid; j < NB; j += 256) {
    base_s[j] = bbase[j] + brsv[blockIdx.x * NB + j];
    rnk[j] = 0;
  }
  __syncthreads();
  int E = E0 + N;
  int b0 = blockIdx.x * chunk, b1 = min(b0 + chunk, E);
  for (int e = b0 + tid; e < b1; e += 256) {
    int src, dst;
    if (e < E0) { src = ldi(ei, e, i64); dst = ldi(ei, (long)E0 + e, i64); }
    else        { src = e - E0; dst = src; }
    int bkt = dst >> 9;
    int r = atomicAdd(&rnk[bkt], 1);
    pairs[base_s[bkt] + r] = ((unsigned)src << 9) | (unsigned)(dst & 511);
  }
}

__global__ void k_bsort(const unsigned* pairs, const int* bbase, int* rowp,
                        int* srcs, int N, int NB, int E) {
  __shared__ int h0[512], sc[512], rk[512];
  int b = blockIdx.x, tid = threadIdx.x;
  int s0 = bbase[b], s1 = bbase[b + 1], L = s1 - s0;
  for (int j = tid; j < 512; j += 256) { h0[j] = 0; rk[j] = 0; }
  __syncthreads();
  for (int i = tid; i < L; i += 256) atomicAdd(&h0[pairs[s0 + i] & 511], 1);
  __syncthreads();
  for (int j = tid; j < 512; j += 256) sc[j] = h0[j];
  __syncthreads();
  for (int ofs = 1; ofs < 512; ofs <<= 1) {
    int j0 = tid, j1 = tid + 256;
    int v0 = (j0 >= ofs) ? sc[j0 - ofs] : 0;
    int v1 = (j1 >= ofs) ? sc[j1 - ofs] : 0;
    __syncthreads();
    sc[j0] += v0; sc[j1] += v1;
    __syncthreads();
  }
  for (int j = tid; j < 512; j += 256) {
    int off = sc[j] - h0[j];
    int node = (b << 9) + j;
    if (node < N) rowp[node] = s0 + off;
    sc[j] = off;
  }
  if (b == 0 && tid == 0) rowp[N] = E;
  __syncthreads();
  for (int i = tid; i < L; i += 256) {
    unsigned p = pairs[s0 + i];
    int j = p & 511;
    int r = atomicAdd(&rk[j], 1);
    srcs[s0 + sc[j] + r] = (int)(p >> 9);
  }
}

// ---------------- K5: layer-1 softmax-aggregate + ELU + fused gemm2 ----------------
__global__ void k_agg1(const float* params, const float* h1, const float* a_s,
                       const float* a_d, const int* rowp, const int* srcs,
                       float4* pk, float* ad2, int N) {
  int n = blockIdx.x * (blockDim.x >> 6) + (threadIdx.x >> 6);
  int lane = threadIdx.x & 63;
  if (n >= N) return;
  int start = rowp[n], end = rowp[n + 1];
  int h = lane & 7, es = lane >> 3;
  float adh = a_d[n * 8 + h];
  float m = -1e30f;
  for (int i = start + es; i < end; i += 8) {
    float e = a_s[srcs[i] * 8 + h] + adh;
    e = e > 0.f ? e : 0.2f * e;
    m = fmaxf(m, e);
  }
  m = fmaxf(m, __shfl_xor(m, 8));
  m = fmaxf(m, __shfl_xor(m, 16));
  m = fmaxf(m, __shfl_xor(m, 32));
  float acc[8] = {0.f,0.f,0.f,0.f,0.f,0.f,0.f,0.f};
  float ssum = 0.f;
  for (int i = start + es; i < end; i += 8) {
    int s = srcs[i];
    float e = a_s[s * 8 + h] + adh;
    e = e > 0.f ? e : 0.2f * e;
    float ex = __expf(e - m);
    ssum += ex;
    const floatx4* hp = (const floatx4*)(h1 + (size_t)s * 64 + h * 8);
    floatx4 u0 = hp[0], u1 = hp[1];
    acc[0] += ex * u0[0]; acc[1] += ex * u0[1]; acc[2] += ex * u0[2]; acc[3] += ex * u0[3];
    acc[4] += ex * u1[0]; acc[5] += ex * u1[1]; acc[6] += ex * u1[2]; acc[7] += ex * u1[3];
  }
#pragma unroll
  for (int msk = 8; msk <= 32; msk <<= 1) {
    ssum += __shfl_xor(ssum, msk);
#pragma unroll
    for (int c = 0; c < 8; c++) acc[c] += __shfl_xor(acc[c], msk);
  }
  if (es == 0) {   // lanes 0..7, lane == h
    float inv = 1.f / (ssum + 1e-16f);
    float pj0 = 0.f, pj1 = 0.f, pj2 = 0.f;
#pragma unroll
    for (int c = 0; c < 8; c++) {
      float v = acc[c] * inv + params[P_B1 + h * 8 + c];
      v = v > 0.f ? v : (__expf(v) - 1.f);   // ELU
      const float* w2r = params + P_W2 + (h * 8 + c) * 3;
      pj0 += v * w2r[0]; pj1 += v * w2r[1]; pj2 += v * w2r[2];
    }
    pj0 += __shfl_xor(pj0, 1); pj1 += __shfl_xor(pj1, 1); pj2 += __shfl_xor(pj2, 1);
    pj0 += __shfl_xor(pj0, 2); pj1 += __shfl_xor(pj1, 2); pj2 += __shfl_xor(pj2, 2);
    pj0 += __shfl_xor(pj0, 4); pj1 += __shfl_xor(pj1, 4); pj2 += __shfl_xor(pj2, 4);
    if (h == 0) {
      float as2 = pj0*params[P_AS2+0] + pj1*params[P_AS2+1] + pj2*params[P_AS2+2];
      float ad2v = pj0*params[P_AD2+0] + pj1*params[P_AD2+1] + pj2*params[P_AD2+2];
      pk[n] = make_float4(pj0, pj1, pj2, as2);
      ad2[n] = ad2v;
    }
  }
}

// ---------------- K7: layer-2 softmax-aggregate + bias -> d_out ----------------
__global__ void k_agg2(const float* params, const float4* pk, const float* ad2,
                       const int* rowp, const int* srcs, void* out, const int* flags, int N) {
  int wid = blockIdx.x * (blockDim.x >> 6) + (threadIdx.x >> 6);
  int lane = threadIdx.x & 63;
  int g = lane >> 4, t = lane & 15;
  int n = wid * 4 + g;
  if (n >= N) return;
  int start = rowp[n], end = rowp[n + 1];
  float ad = ad2[n];
  float m = -1e30f;
  for (int i = start + t; i < end; i += 16) {
    float e = pk[srcs[i]].w + ad;
    e = e > 0.f ? e : 0.2f * e;
    m = fmaxf(m, e);
  }
#pragma unroll
  for (int msk = 1; msk <= 8; msk <<= 1) m = fmaxf(m, __shfl_xor(m, msk));
  float ssum = 0.f, c0 = 0.f, c1 = 0.f, c2 = 0.f;
  for (int i = start + t; i < end; i += 16) {
    float4 v = pk[srcs[i]];
    float e = v.w + ad;
    e = e > 0.f ? e : 0.2f * e;
    float ex = __expf(e - m);
    ssum += ex;
    c0 += ex * v.x; c1 += ex * v.y; c2 += ex * v.z;
  }
#pragma unroll
  for (int msk = 1; msk <= 8; msk <<= 1) {
    ssum += __shfl_xor(ssum, msk);
    c0 += __shfl_xor(c0, msk); c1 += __shfl_xor(c1, msk); c2 += __shfl_xor(c2, msk);
  }
  if (t == 0) {
    float inv = 1.f / (ssum + 1e-16f);
    float o0 = c0 * inv + params[P_B2+0];
    float o1 = c1 * inv + params[P_B2+1];
    float o2 = c2 * inv + params[P_B2+2];
    if (flags[0]) {
      __hip_bfloat16* ob = (__hip_bfloat16*)out;
      ob[n*3+0] = __float2bfloat16(o0);
      ob[n*3+1] = __float2bfloat16(o1);
      ob[n*3+2] = __float2bfloat16(o2);
    } else {
      float* of = (float*)out;
      of[n*3+0] = o0; of[n*3+1] = o1; of[n*3+2] = o2;
    }
  }
}

// ---------------- launch ----------------
extern "C" void kernel_launch(void* const* d_in, const int* in_sizes, int n_in,
                              void* d_out, int out_size, void* d_ws, size_t ws_size,
                              hipStream_t stream) {
  const void* x  = d_in[0];
  const void* ei = d_in[1];
  int N  = in_sizes[0] / 256;   // 100000
  int E0 = in_sizes[1] / 2;     // 3200000
  int E  = E0 + N;
  int NB = (N + 511) >> 9;      // 196 buckets (dst >> 9)
  const int NBLK = 512;
  int chunk = (E + NBLK - 1) / NBLK;

  char* w = (char*)d_ws;
  size_t off = 0;
  auto alloc = [&](size_t bytes) -> char* {
    char* p = w + off;
    off += (bytes + 255) & ~(size_t)255;
    return p;
  };
  int*            flags  = (int*)           alloc(256);
  float*          params = (float*)         alloc(17408 * 4);
  unsigned short* w1t    = (unsigned short*)alloc(16384 * 2);
  float*          h1     = (float*)         alloc((size_t)N * 64 * 4);
  float*          a_s1   = (float*)         alloc((size_t)N * 8 * 4);
  float*          a_d1   = (float*)         alloc((size_t)N * 8 * 4);
  float4*         pk     = (float4*)        alloc((size_t)N * 16);
  float*          ad2    = (float*)         alloc((size_t)N * 4);
  int*            gcnt   = (int*)           alloc(256 * 4);
  int*            bbase  = (int*)           alloc(257 * 4);
  int*            brsv   = (int*)           alloc((size_t)NBLK * NB * 4);
  int*            rowp   = (int*)           alloc((size_t)(N + 1) * 4);
  unsigned*       pairs  = (unsigned*)      alloc((size_t)E * 4);
  int*            srcs   = (int*)           alloc((size_t)E * 4);
  (void)ws_size; (void)n_in; (void)out_size;

  hipMemsetAsync(gcnt, 0, 256 * 4, stream);
  k_prep<<<1, 256, 0, stream>>>(x, ei, d_in[2], d_in[3], d_in[4], d_in[5],
                                d_in[6], d_in[7], d_in[8], d_in[9], flags, params, w1t);
  k_gemm1<<<dim3((N + 63) / 64), 256, 0, stream>>>(x, w1t, flags, params, h1, a_s1, a_d1, N);
  k_bcount<<<dim3(NBLK), 256, 0, stream>>>(ei, flags, gcnt, brsv, E0, N, NB, chunk);
  k_bbase<<<1, 256, 0, stream>>>(gcnt, bbase, NB);
  k_bscatter<<<dim3(NBLK), 256, 0, stream>>>(ei, flags, bbase, brsv, pairs, E0, N, NB, chunk);
  k_bsort<<<dim3(NB), 256, 0, stream>>>(pairs, bbase, rowp, srcs, N, NB, E);
  k_agg1<<<dim3((N + 3) / 4), 256, 0, stream>>>(params, h1, a_s1, a_d1, rowp, srcs, pk, ad2, N);
  k_agg2<<<dim3((N + 15) / 16), 256, 0, stream>>>(params, pk, ad2, rowp, srcs, d_out, flags, N);
}

// Round 6
// 677.846 us; speedup vs baseline: 1.1570x; 1.1570x over previous
//
#include <hip/hip_runtime.h>
#include <hip/hip_bf16.h>

// ---------------- param layout inside ws (floats) ----------------
#define P_W1  0
#define P_AS1 16384
#define P_AD1 16448
#define P_B1  16512
#define P_W2  16576
#define P_AS2 16768
#define P_AD2 16771
#define P_B2  16774

typedef __attribute__((ext_vector_type(8))) short short8;
typedef __attribute__((ext_vector_type(8))) unsigned short ushort8v;
typedef __attribute__((ext_vector_type(4))) float floatx4;

// runtime-dtype load helpers
__device__ __forceinline__ float ldf(const void* p, int i, int bf) {
  if (bf) {
    unsigned v = ((unsigned)((const unsigned short*)p)[i]) << 16;
    float f; __builtin_memcpy(&f, &v, 4); return f;
  }
  return ((const float*)p)[i];
}
__device__ __forceinline__ int ldi(const void* p, long i, int i64) {
  return i64 ? ((const int*)p)[2*i] : ((const int*)p)[i];
}
__device__ __forceinline__ unsigned short f2bfbits(float f) {
  __hip_bfloat16 b = __float2bfloat16(f);
  unsigned short u; __builtin_memcpy(&u, &b, 2); return u;
}
__device__ __forceinline__ float bf2f(unsigned short u) {
  unsigned v = ((unsigned)u) << 16;
  float f; __builtin_memcpy(&f, &v, 4); return f;
}

// ---------------- K0: dtype detection + param conversion ----------------
__global__ void k_prep(const void* x, const void* ei,
                       const void* w1, const void* as1, const void* ad1, const void* b1,
                       const void* w2, const void* as2, const void* ad2, const void* b2,
                       int* flags, float* params, unsigned short* w1t) {
  __shared__ int sh[2];
  int tid = threadIdx.x, lane = tid & 63, w = tid >> 6;
  if (w == 0) {
    const unsigned* xw = (const unsigned*)x;
    int hits = 0;
    for (int i = lane; i < 256; i += 64) {
      unsigned b = (xw[i] >> 7) & 0xFF;
      hits += (b >= 96 && b <= 141) ? 1 : 0;
    }
    for (int o = 32; o >= 1; o >>= 1) hits += __shfl_xor(hits, o);
    if (lane == 0) sh[0] = (hits >= 160) ? 1 : 0;
  } else if (w == 1) {
    const unsigned* ew = (const unsigned*)ei;
    int z = 0;
    for (int i = lane; i < 128; i += 64) z += (ew[2*i+1] == 0u) ? 1 : 0;
    for (int o = 32; o >= 1; o >>= 1) z += __shfl_xor(z, o);
    if (lane == 0) sh[1] = (z >= 64) ? 1 : 0;
  }
  __syncthreads();
  int bf = sh[0];
  if (tid == 0) { flags[0] = sh[0]; flags[1] = sh[1]; }
  for (int i = tid; i < 16384; i += blockDim.x) {
    int ch = i >> 8, k = i & 255;
    w1t[i] = f2bfbits(ldf(w1, k * 64 + ch, bf));
  }
  if (!bf) {
    for (int i = tid; i < 16384; i += blockDim.x) params[P_W1 + i] = ldf(w1, i, bf);
  }
  for (int i = tid; i < 64; i += blockDim.x) {
    params[P_AS1 + i] = ldf(as1, i, bf);
    params[P_AD1 + i] = ldf(ad1, i, bf);
    params[P_B1  + i] = ldf(b1,  i, bf);
  }
  for (int i = tid; i < 192; i += blockDim.x) params[P_W2 + i] = ldf(w2, i, bf);
  for (int i = tid; i < 3; i += blockDim.x) {
    params[P_AS2 + i] = ldf(as2, i, bf);
    params[P_AD2 + i] = ldf(ad2, i, bf);
    params[P_B2  + i] = ldf(b2,  i, bf);
  }
}

// ---------------- CSR build: 2-level bucket sort (bucket = dst >> 9) ----------------
// Runs FIRST (after tiny prep): latency-bound work absorbs the DPM clock-ramp window.
__global__ void k_bcount(const void* ei, const int* flags, int* gcnt, int* brsv,
                         int E0, int N, int NB, int chunk) {
  __shared__ int h[256];
  int i64 = flags[1], tid = threadIdx.x;
  for (int j = tid; j < NB; j += 256) h[j] = 0;
  __syncthreads();
  int E = E0 + N;
  int b0 = blockIdx.x * chunk, b1 = min(b0 + chunk, E);
  for (int e = b0 + tid; e < b1; e += 256) {
    int dst = (e < E0) ? ldi(ei, (long)E0 + e, i64) : (e - E0);
    atomicAdd(&h[dst >> 9], 1);
  }
  __syncthreads();
  for (int j = tid; j < NB; j += 256)
    brsv[blockIdx.x * NB + j] = atomicAdd(&gcnt[j], h[j]);
}

__global__ void k_bbase(const int* gcnt, int* bbase, int NB) {
  __shared__ int sh[256];
  int tid = threadIdx.x;
  sh[tid] = (tid < NB) ? gcnt[tid] : 0;
  __syncthreads();
  int own = sh[tid];
  for (int ofs = 1; ofs < 256; ofs <<= 1) {
    int v = (tid >= ofs) ? sh[tid - ofs] : 0;
    __syncthreads();
    sh[tid] += v;
    __syncthreads();
  }
  if (tid < NB) bbase[tid] = sh[tid] - own;
  if (tid == NB - 1) bbase[NB] = sh[tid];
}

__global__ void k_bscatter(const void* ei, const int* flags, const int* bbase,
                           const int* brsv, unsigned* pairs, int E0, int N, int NB, int chunk) {
  __shared__ int base_s[256];
  __shared__ int rnk[256];
  int i64 = flags[1], tid = threadIdx.x;
  for (int j = tid; j < NB; j += 256) {
    base_s[j] = bbase[j] + brsv[blockIdx.x * NB + j];
    rnk[j] = 0;
  }
  __syncthreads();
  int E = E0 + N;
  int b0 = blockIdx.x * chunk, b1 = min(b0 + chunk, E);
  for (int e = b0 + tid; e < b1; e += 256) {
    int src, dst;
    if (e < E0) { src = ldi(ei, e, i64); dst = ldi(ei, (long)E0 + e, i64); }
    else        { src = e - E0; dst = src; }
    int bkt = dst >> 9;
    int r = atomicAdd(&rnk[bkt], 1);
    pairs[base_s[bkt] + r] = ((unsigned)src << 9) | (unsigned)(dst & 511);
  }
}

__global__ void k_bsort(const unsigned* pairs, const int* bbase, int* rowp,
                        int* srcs, int N, int NB, int E) {
  __shared__ int h0[512], sc[512], rk[512];
  int b = blockIdx.x, tid = threadIdx.x;
  int s0 = bbase[b], s1 = bbase[b + 1], L = s1 - s0;
  for (int j = tid; j < 512; j += 256) { h0[j] = 0; rk[j] = 0; }
  __syncthreads();
  for (int i = tid; i < L; i += 256) atomicAdd(&h0[pairs[s0 + i] & 511], 1);
  __syncthreads();
  for (int j = tid; j < 512; j += 256) sc[j] = h0[j];
  __syncthreads();
  for (int ofs = 1; ofs < 512; ofs <<= 1) {
    int j0 = tid, j1 = tid + 256;
    int v0 = (j0 >= ofs) ? sc[j0 - ofs] : 0;
    int v1 = (j1 >= ofs) ? sc[j1 - ofs] : 0;
    __syncthreads();
    sc[j0] += v0; sc[j1] += v1;
    __syncthreads();
  }
  for (int j = tid; j < 512; j += 256) {
    int off = sc[j] - h0[j];
    int node = (b << 9) + j;
    if (node < N) rowp[node] = s0 + off;
    sc[j] = off;
  }
  if (b == 0 && tid == 0) rowp[N] = E;
  __syncthreads();
  for (int i = tid; i < L; i += 256) {
    unsigned p = pairs[s0 + i];
    int j = p & 511;
    int r = atomicAdd(&rk[j], 1);
    srcs[s0 + sc[j] + r] = (int)(p >> 9);
  }
}

// ---------------- K1: h1 = x @ W1 via MFMA (R4 structure), h1 stored bf16 ----------------
#define XP 272   // LDS row pitch in bf16 elems

__device__ __forceinline__ void gemm1_f32(const float* x, const float* params,
                                          unsigned short* h1, float* a_s, float* a_d,
                                          int N, int wave, int lane) {
  int n0 = wave * 4;
  if (n0 >= N) return;
  int nb[4];
#pragma unroll
  for (int j = 0; j < 4; j++) nb[j] = min(n0 + j, N - 1) * 256;
  float acc[4] = {0.f, 0.f, 0.f, 0.f};
  const float* W = params + P_W1;
  for (int k = 0; k < 256; k++) {
    float wv = W[k * 64 + lane];
#pragma unroll
    for (int j = 0; j < 4; j++) acc[j] += x[nb[j] + k] * wv;
  }
  float as1v = params[P_AS1 + lane], ad1v = params[P_AD1 + lane];
#pragma unroll
  for (int j = 0; j < 4; j++) {
    int n = n0 + j;
    if (n >= N) break;
    float hv = acc[j];
    float s = hv * as1v, d = hv * ad1v;
    s += __shfl_xor(s, 1); s += __shfl_xor(s, 2); s += __shfl_xor(s, 4);
    d += __shfl_xor(d, 1); d += __shfl_xor(d, 2); d += __shfl_xor(d, 4);
    h1[(size_t)n * 64 + lane] = f2bfbits(hv);
    if ((lane & 7) == 0) {
      a_s[n * 8 + (lane >> 3)] = s;
      a_d[n * 8 + (lane >> 3)] = d;
    }
  }
}

__global__ void k_gemm1(const void* x, const unsigned short* w1t, const int* flags,
                        const float* params, unsigned short* h1, float* a_s, float* a_d, int N) {
  __shared__ unsigned short xs[16 * XP];
  int tid = threadIdx.x;
  int wv = tid >> 6, lane = tid & 63;
  if (flags[0]) {
    const unsigned short* xb = (const unsigned short*)x;
    int n0 = blockIdx.x * 16;
#pragma unroll
    for (int it = 0; it < 2; it++) {
      int idx = tid + it * 256;
      int row = idx >> 5, col = idx & 31;
      int gn = n0 + row; if (gn >= N) gn = N - 1;
      uint4 v = *(const uint4*)(xb + (size_t)gn * 256 + col * 8);
      *(uint4*)(xs + row * XP + col * 8) = v;
    }
    __syncthreads();
    int quad = lane >> 4, l16 = lane & 15;
    int ch = wv * 16 + l16;
    floatx4 acc = {0.f, 0.f, 0.f, 0.f};
    const unsigned short* xrow = xs + l16 * XP + quad * 8;
    const unsigned short* wrow = w1t + (size_t)ch * 256 + quad * 8;
#pragma unroll
    for (int k0 = 0; k0 < 256; k0 += 32) {
      short8 a = *(const short8*)(xrow + k0);
      short8 b = *(const short8*)(wrow + k0);
      acc = __builtin_amdgcn_mfma_f32_16x16x32_bf16(a, b, acc, 0, 0, 0);
    }
    float asv = params[P_AS1 + ch], adv = params[P_AD1 + ch];
#pragma unroll
    for (int r = 0; r < 4; r++) {
      int n = n0 + quad * 4 + r;           // C/D: col=lane&15 (ch), row=quad*4+reg (node)
      if (n >= N) break;
      float d = acc[r];
      h1[(size_t)n * 64 + ch] = f2bfbits(d);
      float s = d * asv, t = d * adv;
      s += __shfl_xor(s, 1); s += __shfl_xor(s, 2); s += __shfl_xor(s, 4);
      t += __shfl_xor(t, 1); t += __shfl_xor(t, 2); t += __shfl_xor(t, 4);
      if ((lane & 7) == 0) {
        int head = ch >> 3;
        a_s[n * 8 + head] = s;
        a_d[n * 8 + head] = t;
      }
    }
  } else {
    gemm1_f32((const float*)x, params, h1, a_s, a_d, N, blockIdx.x * 4 + wv, lane);
  }
}

// ---------------- K5: layer-1 softmax-aggregate + ELU + fused gemm2 (bf16 h1 gathers) ----------------
__global__ void k_agg1(const float* params, const unsigned short* h1, const float* a_s,
                       const float* a_d, const int* rowp, const int* srcs,
                       float4* pk, float* ad2, int N) {
  int n = blockIdx.x * (blockDim.x >> 6) + (threadIdx.x >> 6);
  int lane = threadIdx.x & 63;
  if (n >= N) return;
  int start = rowp[n], end = rowp[n + 1];
  int h = lane & 7, es = lane >> 3;
  float adh = a_d[n * 8 + h];
  float m = -1e30f;
  for (int i = start + es; i < end; i += 8) {
    float e = a_s[srcs[i] * 8 + h] + adh;
    e = e > 0.f ? e : 0.2f * e;
    m = fmaxf(m, e);
  }
  m = fmaxf(m, __shfl_xor(m, 8));
  m = fmaxf(m, __shfl_xor(m, 16));
  m = fmaxf(m, __shfl_xor(m, 32));
  float acc[8] = {0.f,0.f,0.f,0.f,0.f,0.f,0.f,0.f};
  float ssum = 0.f;
  for (int i = start + es; i < end; i += 8) {
    int s = srcs[i];
    float e = a_s[s * 8 + h] + adh;
    e = e > 0.f ? e : 0.2f * e;
    float ex = __expf(e - m);
    ssum += ex;
    ushort8v u = *(const ushort8v*)(h1 + (size_t)s * 64 + h * 8);  // 16B gather
#pragma unroll
    for (int c = 0; c < 8; c++) acc[c] += ex * bf2f(u[c]);
  }
#pragma unroll
  for (int msk = 8; msk <= 32; msk <<= 1) {
    ssum += __shfl_xor(ssum, msk);
#pragma unroll
    for (int c = 0; c < 8; c++) acc[c] += __shfl_xor(acc[c], msk);
  }
  if (es == 0) {   // lanes 0..7, lane == h
    float inv = 1.f / (ssum + 1e-16f);
    float pj0 = 0.f, pj1 = 0.f, pj2 = 0.f;
#pragma unroll
    for (int c = 0; c < 8; c++) {
      float v = acc[c] * inv + params[P_B1 + h * 8 + c];
      v = v > 0.f ? v : (__expf(v) - 1.f);   // ELU
      const float* w2r = params + P_W2 + (h * 8 + c) * 3;
      pj0 += v * w2r[0]; pj1 += v * w2r[1]; pj2 += v * w2r[2];
    }
    pj0 += __shfl_xor(pj0, 1); pj1 += __shfl_xor(pj1, 1); pj2 += __shfl_xor(pj2, 1);
    pj0 += __shfl_xor(pj0, 2); pj1 += __shfl_xor(pj1, 2); pj2 += __shfl_xor(pj2, 2);
    pj0 += __shfl_xor(pj0, 4); pj1 += __shfl_xor(pj1, 4); pj2 += __shfl_xor(pj2, 4);
    if (h == 0) {
      float as2 = pj0*params[P_AS2+0] + pj1*params[P_AS2+1] + pj2*params[P_AS2+2];
      float ad2v = pj0*params[P_AD2+0] + pj1*params[P_AD2+1] + pj2*params[P_AD2+2];
      pk[n] = make_float4(pj0, pj1, pj2, as2);
      ad2[n] = ad2v;
    }
  }
}

// ---------------- K7: layer-2 softmax-aggregate + bias -> d_out ----------------
__global__ void k_agg2(const float* params, const float4* pk, const float* ad2,
                       const int* rowp, const int* srcs, void* out, const int* flags, int N) {
  int wid = blockIdx.x * (blockDim.x >> 6) + (threadIdx.x >> 6);
  int lane = threadIdx.x & 63;
  int g = lane >> 4, t = lane & 15;
  int n = wid * 4 + g;
  if (n >= N) return;
  int start = rowp[n], end = rowp[n + 1];
  float ad = ad2[n];
  float m = -1e30f;
  for (int i = start + t; i < end; i += 16) {
    float e = pk[srcs[i]].w + ad;
    e = e > 0.f ? e : 0.2f * e;
    m = fmaxf(m, e);
  }
#pragma unroll
  for (int msk = 1; msk <= 8; msk <<= 1) m = fmaxf(m, __shfl_xor(m, msk));
  float ssum = 0.f, c0 = 0.f, c1 = 0.f, c2 = 0.f;
  for (int i = start + t; i < end; i += 16) {
    float4 v = pk[srcs[i]];
    float e = v.w + ad;
    e = e > 0.f ? e : 0.2f * e;
    float ex = __expf(e - m);
    ssum += ex;
    c0 += ex * v.x; c1 += ex * v.y; c2 += ex * v.z;
  }
#pragma unroll
  for (int msk = 1; msk <= 8; msk <<= 1) {
    ssum += __shfl_xor(ssum, msk);
    c0 += __shfl_xor(c0, msk); c1 += __shfl_xor(c1, msk); c2 += __shfl_xor(c2, msk);
  }
  if (t == 0) {
    float inv = 1.f / (ssum + 1e-16f);
    float o0 = c0 * inv + params[P_B2+0];
    float o1 = c1 * inv + params[P_B2+1];
    float o2 = c2 * inv + params[P_B2+2];
    if (flags[0]) {
      __hip_bfloat16* ob = (__hip_bfloat16*)out;
      ob[n*3+0] = __float2bfloat16(o0);
      ob[n*3+1] = __float2bfloat16(o1);
      ob[n*3+2] = __float2bfloat16(o2);
    } else {
      float* of = (float*)out;
      of[n*3+0] = o0; of[n*3+1] = o1; of[n*3+2] = o2;
    }
  }
}

// ---------------- launch ----------------
extern "C" void kernel_launch(void* const* d_in, const int* in_sizes, int n_in,
                              void* d_out, int out_size, void* d_ws, size_t ws_size,
                              hipStream_t stream) {
  const void* x  = d_in[0];
  const void* ei = d_in[1];
  int N  = in_sizes[0] / 256;   // 100000
  int E0 = in_sizes[1] / 2;     // 3200000
  int E  = E0 + N;
  int NB = (N + 511) >> 9;      // 196 buckets (dst >> 9)
  const int NBLK = 512;
  int chunk = (E + NBLK - 1) / NBLK;

  char* w = (char*)d_ws;
  size_t off = 0;
  auto alloc = [&](size_t bytes) -> char* {
    char* p = w + off;
    off += (bytes + 255) & ~(size_t)255;
    return p;
  };
  int*            flags  = (int*)           alloc(256);
  float*          params = (float*)         alloc(17408 * 4);
  unsigned short* w1t    = (unsigned short*)alloc(16384 * 2);
  unsigned short* h1     = (unsigned short*)alloc((size_t)N * 64 * 2);
  float*          a_s1   = (float*)         alloc((size_t)N * 8 * 4);
  float*          a_d1   = (float*)         alloc((size_t)N * 8 * 4);
  float4*         pk     = (float4*)        alloc((size_t)N * 16);
  float*          ad2    = (float*)         alloc((size_t)N * 4);
  int*            gcnt   = (int*)           alloc(256 * 4);
  int*            bbase  = (int*)           alloc(257 * 4);
  int*            brsv   = (int*)           alloc((size_t)NBLK * NB * 4);
  int*            rowp   = (int*)           alloc((size_t)(N + 1) * 4);
  unsigned*       pairs  = (unsigned*)      alloc((size_t)E * 4);
  int*            srcs   = (int*)           alloc((size_t)E * 4);
  (void)ws_size; (void)n_in; (void)out_size;

  hipMemsetAsync(gcnt, 0, 256 * 4, stream);
  k_prep<<<1, 256, 0, stream>>>(x, ei, d_in[2], d_in[3], d_in[4], d_in[5],
                                d_in[6], d_in[7], d_in[8], d_in[9], flags, params, w1t);
  // CSR build first: latency-bound, absorbs the clock-ramp window
  k_bcount<<<dim3(NBLK), 256, 0, stream>>>(ei, flags, gcnt, brsv, E0, N, NB, chunk);
  k_bbase<<<1, 256, 0, stream>>>(gcnt, bbase, NB);
  k_bscatter<<<dim3(NBLK), 256, 0, stream>>>(ei, flags, bbase, brsv, pairs, E0, N, NB, chunk);
  k_bsort<<<dim3(NB), 256, 0, stream>>>(pairs, bbase, rowp, srcs, N, NB, E);
  // compute-heavy kernels after clocks ramp
  k_gemm1<<<dim3((N + 15) / 16), 256, 0, stream>>>(x, w1t, flags, params, h1, a_s1, a_d1, N);
  k_agg1<<<dim3((N + 3) / 4), 256, 0, stream>>>(params, h1, a_s1, a_d1, rowp, srcs, pk, ad2, N);
  k_agg2<<<dim3((N + 15) / 16), 256, 0, stream>>>(params, pk, ad2, rowp, srcs, d_out, flags, N);
}

// Round 7
// 676.316 us; speedup vs baseline: 1.1596x; 1.0023x over previous
//
#include <hip/hip_runtime.h>
#include <hip/hip_bf16.h>

// ---------------- param layout inside ws (floats) ----------------
#define P_W1  0
#define P_AS1 16384
#define P_AD1 16448
#define P_B1  16512
#define P_W2  16576
#define P_AS2 16768
#define P_AD2 16771
#define P_B2  16774

#define NBLK_CSR 512
#define CXB      768

typedef __attribute__((ext_vector_type(8))) short short8;
typedef __attribute__((ext_vector_type(8))) unsigned short ushort8v;
typedef __attribute__((ext_vector_type(4))) float floatx4;

// runtime-dtype load helpers
__device__ __forceinline__ float ldf(const void* p, int i, int bf) {
  if (bf) {
    unsigned v = ((unsigned)((const unsigned short*)p)[i]) << 16;
    float f; __builtin_memcpy(&f, &v, 4); return f;
  }
  return ((const float*)p)[i];
}
__device__ __forceinline__ int ldi(const void* p, long i, int i64) {
  return i64 ? ((const int*)p)[2*i] : ((const int*)p)[i];
}
__device__ __forceinline__ unsigned short f2bfbits(float f) {
  __hip_bfloat16 b = __float2bfloat16(f);
  unsigned short u; __builtin_memcpy(&u, &b, 2); return u;
}
__device__ __forceinline__ float bf2f(unsigned short u) {
  unsigned v = ((unsigned)u) << 16;
  float f; __builtin_memcpy(&f, &v, 4); return f;
}

// ---------------- K0: dtype detection + param conversion ----------------
__global__ void k_prep(const void* x, const void* ei,
                       const void* w1, const void* as1, const void* ad1, const void* b1,
                       const void* w2, const void* as2, const void* ad2, const void* b2,
                       int* flags, float* params, unsigned short* w1t) {
  __shared__ int sh[2];
  int tid = threadIdx.x, lane = tid & 63, w = tid >> 6;
  if (w == 0) {
    const unsigned* xw = (const unsigned*)x;
    int hits = 0;
    for (int i = lane; i < 256; i += 64) {
      unsigned b = (xw[i] >> 7) & 0xFF;
      hits += (b >= 96 && b <= 141) ? 1 : 0;
    }
    for (int o = 32; o >= 1; o >>= 1) hits += __shfl_xor(hits, o);
    if (lane == 0) sh[0] = (hits >= 160) ? 1 : 0;
  } else if (w == 1) {
    const unsigned* ew = (const unsigned*)ei;
    int z = 0;
    for (int i = lane; i < 128; i += 64) z += (ew[2*i+1] == 0u) ? 1 : 0;
    for (int o = 32; o >= 1; o >>= 1) z += __shfl_xor(z, o);
    if (lane == 0) sh[1] = (z >= 64) ? 1 : 0;
  }
  __syncthreads();
  int bf = sh[0];
  if (tid == 0) { flags[0] = sh[0]; flags[1] = sh[1]; }
  for (int i = tid; i < 16384; i += blockDim.x) {
    int ch = i >> 8, k = i & 255;
    w1t[i] = f2bfbits(ldf(w1, k * 64 + ch, bf));
  }
  if (!bf) {
    for (int i = tid; i < 16384; i += blockDim.x) params[P_W1 + i] = ldf(w1, i, bf);
  }
  for (int i = tid; i < 64; i += blockDim.x) {
    params[P_AS1 + i] = ldf(as1, i, bf);
    params[P_AD1 + i] = ldf(ad1, i, bf);
    params[P_B1  + i] = ldf(b1,  i, bf);
  }
  for (int i = tid; i < 192; i += blockDim.x) params[P_W2 + i] = ldf(w2, i, bf);
  for (int i = tid; i < 3; i += blockDim.x) {
    params[P_AS2 + i] = ldf(as2, i, bf);
    params[P_AD2 + i] = ldf(ad2, i, bf);
    params[P_B2  + i] = ldf(b2,  i, bf);
  }
}

// ---------------- K2a (fused): CSR bucket histogram  +  streaming copy x -> ws ----------------
// Blocks [0,NBLK_CSR): per-block bucket histogram of dst (bucket = dst>>9).
// Blocks [NBLK_CSR, NBLK_CSR+CXB): grid-stride uint4 copy of x into xcopy.
// Both passes read a d_in buffer exactly once; they overlap in one dispatch.
__global__ void k_bcount(const void* ei, const int* flags, int* gcnt, int* brsv,
                         int E0, int N, int NB, int chunk,
                         const void* x, uint4* xcopy) {
  __shared__ int h[256];
  int tid = threadIdx.x;
  if (blockIdx.x >= NBLK_CSR) {
    if (flags[0]) {   // bf16 path only; f32 fallback reads x directly later
      const uint4* xs4 = (const uint4*)x;
      long n16 = (long)N * 32;                       // N*256 bf16 = N*512 B = N*32 uint4
      long stride = (long)CXB * 256;
      for (long i = (long)(blockIdx.x - NBLK_CSR) * 256 + tid; i < n16; i += stride)
        xcopy[i] = xs4[i];
    }
    return;
  }
  int i64 = flags[1];
  for (int j = tid; j < NB; j += 256) h[j] = 0;
  __syncthreads();
  int E = E0 + N;
  int b0 = blockIdx.x * chunk, b1 = min(b0 + chunk, E);
  for (int e = b0 + tid; e < b1; e += 256) {
    int dst = (e < E0) ? ldi(ei, (long)E0 + e, i64) : (e - E0);
    atomicAdd(&h[dst >> 9], 1);
  }
  __syncthreads();
  for (int j = tid; j < NB; j += 256)
    brsv[blockIdx.x * NB + j] = atomicAdd(&gcnt[j], h[j]);
}

__global__ void k_bbase(const int* gcnt, int* bbase, int NB) {
  __shared__ int sh[256];
  int tid = threadIdx.x;
  sh[tid] = (tid < NB) ? gcnt[tid] : 0;
  __syncthreads();
  int own = sh[tid];
  for (int ofs = 1; ofs < 256; ofs <<= 1) {
    int v = (tid >= ofs) ? sh[tid - ofs] : 0;
    __syncthreads();
    sh[tid] += v;
    __syncthreads();
  }
  if (tid < NB) bbase[tid] = sh[tid] - own;
  if (tid == NB - 1) bbase[NB] = sh[tid];
}

__global__ void k_bscatter(const void* ei, const int* flags, const int* bbase,
                           const int* brsv, unsigned* pairs, int E0, int N, int NB, int chunk) {
  __shared__ int base_s[256];
  __shared__ int rnk[256];
  int i64 = flags[1], tid = threadIdx.x;
  for (int j = tid; j < NB; j += 256) {
    base_s[j] = bbase[j] + brsv[blockIdx.x * NB + j];
    rnk[j] = 0;
  }
  __syncthreads();
  int E = E0 + N;
  int b0 = blockIdx.x * chunk, b1 = min(b0 + chunk, E);
  for (int e = b0 + tid; e < b1; e += 256) {
    int src, dst;
    if (e < E0) { src = ldi(ei, e, i64); dst = ldi(ei, (long)E0 + e, i64); }
    else        { src = e - E0; dst = src; }
    int bkt = dst >> 9;
    int r = atomicAdd(&rnk[bkt], 1);
    pairs[base_s[bkt] + r] = ((unsigned)src << 9) | (unsigned)(dst & 511);
  }
}

__global__ void k_bsort(const unsigned* pairs, const int* bbase, int* rowp,
                        int* srcs, int N, int NB, int E) {
  __shared__ int h0[512], sc[512], rk[512];
  int b = blockIdx.x, tid = threadIdx.x;
  int s0 = bbase[b], s1 = bbase[b + 1], L = s1 - s0;
  for (int j = tid; j < 512; j += 256) { h0[j] = 0; rk[j] = 0; }
  __syncthreads();
  for (int i = tid; i < L; i += 256) atomicAdd(&h0[pairs[s0 + i] & 511], 1);
  __syncthreads();
  for (int j = tid; j < 512; j += 256) sc[j] = h0[j];
  __syncthreads();
  for (int ofs = 1; ofs < 512; ofs <<= 1) {
    int j0 = tid, j1 = tid + 256;
    int v0 = (j0 >= ofs) ? sc[j0 - ofs] : 0;
    int v1 = (j1 >= ofs) ? sc[j1 - ofs] : 0;
    __syncthreads();
    sc[j0] += v0; sc[j1] += v1;
    __syncthreads();
  }
  for (int j = tid; j < 512; j += 256) {
    int off = sc[j] - h0[j];
    int node = (b << 9) + j;
    if (node < N) rowp[node] = s0 + off;
    sc[j] = off;
  }
  if (b == 0 && tid == 0) rowp[N] = E;
  __syncthreads();
  for (int i = tid; i < L; i += 256) {
    unsigned p = pairs[s0 + i];
    int j = p & 511;
    int r = atomicAdd(&rk[j], 1);
    srcs[s0 + sc[j] + r] = (int)(p >> 9);
  }
}

// ---------------- K1: h1 = xcopy @ W1 via MFMA (R4/R6 structure), h1 stored bf16 ----------------
#define XP 272   // LDS row pitch in bf16 elems

__device__ __forceinline__ void gemm1_f32(const float* x, const float* params,
                                          unsigned short* h1, float* a_s, float* a_d,
                                          int N, int wave, int lane) {
  int n0 = wave * 4;
  if (n0 >= N) return;
  int nb[4];
#pragma unroll
  for (int j = 0; j < 4; j++) nb[j] = min(n0 + j, N - 1) * 256;
  float acc[4] = {0.f, 0.f, 0.f, 0.f};
  const float* W = params + P_W1;
  for (int k = 0; k < 256; k++) {
    float wv = W[k * 64 + lane];
#pragma unroll
    for (int j = 0; j < 4; j++) acc[j] += x[nb[j] + k] * wv;
  }
  float as1v = params[P_AS1 + lane], ad1v = params[P_AD1 + lane];
#pragma unroll
  for (int j = 0; j < 4; j++) {
    int n = n0 + j;
    if (n >= N) break;
    float hv = acc[j];
    float s = hv * as1v, d = hv * ad1v;
    s += __shfl_xor(s, 1); s += __shfl_xor(s, 2); s += __shfl_xor(s, 4);
    d += __shfl_xor(d, 1); d += __shfl_xor(d, 2); d += __shfl_xor(d, 4);
    h1[(size_t)n * 64 + lane] = f2bfbits(hv);
    if ((lane & 7) == 0) {
      a_s[n * 8 + (lane >> 3)] = s;
      a_d[n * 8 + (lane >> 3)] = d;
    }
  }
}

__global__ void k_gemm1(const void* x, const unsigned short* xcopy, const unsigned short* w1t,
                        const int* flags, const float* params,
                        unsigned short* h1, float* a_s, float* a_d, int N) {
  __shared__ unsigned short xs[16 * XP];
  int tid = threadIdx.x;
  int wv = tid >> 6, lane = tid & 63;
  if (flags[0]) {
    int n0 = blockIdx.x * 16;
#pragma unroll
    for (int it = 0; it < 2; it++) {
      int idx = tid + it * 256;
      int row = idx >> 5, col = idx & 31;
      int gn = n0 + row; if (gn >= N) gn = N - 1;
      uint4 v = *(const uint4*)(xcopy + (size_t)gn * 256 + col * 8);
      *(uint4*)(xs + row * XP + col * 8) = v;
    }
    __syncthreads();
    int quad = lane >> 4, l16 = lane & 15;
    int ch = wv * 16 + l16;
    floatx4 acc = {0.f, 0.f, 0.f, 0.f};
    const unsigned short* xrow = xs + l16 * XP + quad * 8;
    const unsigned short* wrow = w1t + (size_t)ch * 256 + quad * 8;
#pragma unroll
    for (int k0 = 0; k0 < 256; k0 += 32) {
      short8 a = *(const short8*)(xrow + k0);
      short8 b = *(const short8*)(wrow + k0);
      acc = __builtin_amdgcn_mfma_f32_16x16x32_bf16(a, b, acc, 0, 0, 0);
    }
    float asv = params[P_AS1 + ch], adv = params[P_AD1 + ch];
#pragma unroll
    for (int r = 0; r < 4; r++) {
      int n = n0 + quad * 4 + r;           // C/D: col=lane&15 (ch), row=quad*4+reg (node)
      if (n >= N) break;
      float d = acc[r];
      h1[(size_t)n * 64 + ch] = f2bfbits(d);
      float s = d * asv, t = d * adv;
      s += __shfl_xor(s, 1); s += __shfl_xor(s, 2); s += __shfl_xor(s, 4);
      t += __shfl_xor(t, 1); t += __shfl_xor(t, 2); t += __shfl_xor(t, 4);
      if ((lane & 7) == 0) {
        int head = ch >> 3;
        a_s[n * 8 + head] = s;
        a_d[n * 8 + head] = t;
      }
    }
  } else {
    gemm1_f32((const float*)x, params, h1, a_s, a_d, N, blockIdx.x * 4 + wv, lane);
  }
}

// ---------------- K5: layer-1 softmax-aggregate + ELU + fused gemm2 (bf16 h1 gathers) ----------------
__global__ void k_agg1(const float* params, const unsigned short* h1, const float* a_s,
                       const float* a_d, const int* rowp, const int* srcs,
                       float4* pk, float* ad2, int N) {
  int n = blockIdx.x * (blockDim.x >> 6) + (threadIdx.x >> 6);
  int lane = threadIdx.x & 63;
  if (n >= N) return;
  int start = rowp[n], end = rowp[n + 1];
  int h = lane & 7, es = lane >> 3;
  float adh = a_d[n * 8 + h];
  float m = -1e30f;
  for (int i = start + es; i < end; i += 8) {
    float e = a_s[srcs[i] * 8 + h] + adh;
    e = e > 0.f ? e : 0.2f * e;
    m = fmaxf(m, e);
  }
  m = fmaxf(m, __shfl_xor(m, 8));
  m = fmaxf(m, __shfl_xor(m, 16));
  m = fmaxf(m, __shfl_xor(m, 32));
  float acc[8] = {0.f,0.f,0.f,0.f,0.f,0.f,0.f,0.f};
  float ssum = 0.f;
  for (int i = start + es; i < end; i += 8) {
    int s = srcs[i];
    float e = a_s[s * 8 + h] + adh;
    e = e > 0.f ? e : 0.2f * e;
    float ex = __expf(e - m);
    ssum += ex;
    ushort8v u = *(const ushort8v*)(h1 + (size_t)s * 64 + h * 8);  // 16B gather
#pragma unroll
    for (int c = 0; c < 8; c++) acc[c] += ex * bf2f(u[c]);
  }
#pragma unroll
  for (int msk = 8; msk <= 32; msk <<= 1) {
    ssum += __shfl_xor(ssum, msk);
#pragma unroll
    for (int c = 0; c < 8; c++) acc[c] += __shfl_xor(acc[c], msk);
  }
  if (es == 0) {   // lanes 0..7, lane == h
    float inv = 1.f / (ssum + 1e-16f);
    float pj0 = 0.f, pj1 = 0.f, pj2 = 0.f;
#pragma unroll
    for (int c = 0; c < 8; c++) {
      float v = acc[c] * inv + params[P_B1 + h * 8 + c];
      v = v > 0.f ? v : (__expf(v) - 1.f);   // ELU
      const float* w2r = params + P_W2 + (h * 8 + c) * 3;
      pj0 += v * w2r[0]; pj1 += v * w2r[1]; pj2 += v * w2r[2];
    }
    pj0 += __shfl_xor(pj0, 1); pj1 += __shfl_xor(pj1, 1); pj2 += __shfl_xor(pj2, 1);
    pj0 += __shfl_xor(pj0, 2); pj1 += __shfl_xor(pj1, 2); pj2 += __shfl_xor(pj2, 2);
    pj0 += __shfl_xor(pj0, 4); pj1 += __shfl_xor(pj1, 4); pj2 += __shfl_xor(pj2, 4);
    if (h == 0) {
      float as2 = pj0*params[P_AS2+0] + pj1*params[P_AS2+1] + pj2*params[P_AS2+2];
      float ad2v = pj0*params[P_AD2+0] + pj1*params[P_AD2+1] + pj2*params[P_AD2+2];
      pk[n] = make_float4(pj0, pj1, pj2, as2);
      ad2[n] = ad2v;
    }
  }
}

// ---------------- K7: layer-2 softmax-aggregate + bias -> d_out ----------------
__global__ void k_agg2(const float* params, const float4* pk, const float* ad2,
                       const int* rowp, const int* srcs, void* out, const int* flags, int N) {
  int wid = blockIdx.x * (blockDim.x >> 6) + (threadIdx.x >> 6);
  int lane = threadIdx.x & 63;
  int g = lane >> 4, t = lane & 15;
  int n = wid * 4 + g;
  if (n >= N) return;
  int start = rowp[n], end = rowp[n + 1];
  float ad = ad2[n];
  float m = -1e30f;
  for (int i = start + t; i < end; i += 16) {
    float e = pk[srcs[i]].w + ad;
    e = e > 0.f ? e : 0.2f * e;
    m = fmaxf(m, e);
  }
#pragma unroll
  for (int msk = 1; msk <= 8; msk <<= 1) m = fmaxf(m, __shfl_xor(m, msk));
  float ssum = 0.f, c0 = 0.f, c1 = 0.f, c2 = 0.f;
  for (int i = start + t; i < end; i += 16) {
    float4 v = pk[srcs[i]];
    float e = v.w + ad;
    e = e > 0.f ? e : 0.2f * e;
    float ex = __expf(e - m);
    ssum += ex;
    c0 += ex * v.x; c1 += ex * v.y; c2 += ex * v.z;
  }
#pragma unroll
  for (int msk = 1; msk <= 8; msk <<= 1) {
    ssum += __shfl_xor(ssum, msk);
    c0 += __shfl_xor(c0, msk); c1 += __shfl_xor(c1, msk); c2 += __shfl_xor(c2, msk);
  }
  if (t == 0) {
    float inv = 1.f / (ssum + 1e-16f);
    float o0 = c0 * inv + params[P_B2+0];
    float o1 = c1 * inv + params[P_B2+1];
    float o2 = c2 * inv + params[P_B2+2];
    if (flags[0]) {
      __hip_bfloat16* ob = (__hip_bfloat16*)out;
      ob[n*3+0] = __float2bfloat16(o0);
      ob[n*3+1] = __float2bfloat16(o1);
      ob[n*3+2] = __float2bfloat16(o2);
    } else {
      float* of = (float*)out;
      of[n*3+0] = o0; of[n*3+1] = o1; of[n*3+2] = o2;
    }
  }
}

// ---------------- launch ----------------
extern "C" void kernel_launch(void* const* d_in, const int* in_sizes, int n_in,
                              void* d_out, int out_size, void* d_ws, size_t ws_size,
                              hipStream_t stream) {
  const void* x  = d_in[0];
  const void* ei = d_in[1];
  int N  = in_sizes[0] / 256;   // 100000
  int E0 = in_sizes[1] / 2;     // 3200000
  int E  = E0 + N;
  int NB = (N + 511) >> 9;      // 196 buckets (dst >> 9)
  int chunk = (E + NBLK_CSR - 1) / NBLK_CSR;

  char* w = (char*)d_ws;
  size_t off = 0;
  auto alloc = [&](size_t bytes) -> char* {
    char* p = w + off;
    off += (bytes + 255) & ~(size_t)255;
    return p;
  };
  int*            flags  = (int*)           alloc(256);
  float*          params = (float*)         alloc(17408 * 4);
  unsigned short* w1t    = (unsigned short*)alloc(16384 * 2);
  unsigned short* h1     = (unsigned short*)alloc((size_t)N * 64 * 2);
  float*          a_s1   = (float*)         alloc((size_t)N * 8 * 4);
  float*          a_d1   = (float*)         alloc((size_t)N * 8 * 4);
  float4*         pk     = (float4*)        alloc((size_t)N * 16);
  float*          ad2    = (float*)         alloc((size_t)N * 4);
  int*            gcnt   = (int*)           alloc(256 * 4);
  int*            bbase  = (int*)           alloc(257 * 4);
  int*            brsv   = (int*)           alloc((size_t)NBLK_CSR * NB * 4);
  int*            rowp   = (int*)           alloc((size_t)(N + 1) * 4);
  unsigned*       pairs  = (unsigned*)      alloc((size_t)E * 4);
  int*            srcs   = (int*)           alloc((size_t)E * 4);
  unsigned short* xcopy  = (unsigned short*)alloc((size_t)N * 256 * 2);  // 51.2 MB (bf16 path)
  (void)ws_size; (void)n_in; (void)out_size;

  hipMemsetAsync(gcnt, 0, 256 * 4, stream);
  k_prep<<<1, 256, 0, stream>>>(x, ei, d_in[2], d_in[3], d_in[4], d_in[5],
                                d_in[6], d_in[7], d_in[8], d_in[9], flags, params, w1t);
  // fused: CSR histogram (slow ei pass) + streaming x copy (slow x pass) overlap
  k_bcount<<<dim3(NBLK_CSR + CXB), 256, 0, stream>>>(ei, flags, gcnt, brsv, E0, N, NB, chunk,
                                                     x, (uint4*)xcopy);
  k_bbase<<<1, 256, 0, stream>>>(gcnt, bbase, NB);
  k_bscatter<<<dim3(NBLK_CSR), 256, 0, stream>>>(ei, flags, bbase, brsv, pairs, E0, N, NB, chunk);
  k_bsort<<<dim3(NB), 256, 0, stream>>>(pairs, bbase, rowp, srcs, N, NB, E);
  k_gemm1<<<dim3((N + 15) / 16), 256, 0, stream>>>(x, xcopy, w1t, flags, params, h1, a_s1, a_d1, N);
  k_agg1<<<dim3((N + 3) / 4), 256, 0, stream>>>(params, h1, a_s1, a_d1, rowp, srcs, pk, ad2, N);
  k_agg2<<<dim3((N + 15) / 16), 256, 0, stream>>>(params, pk, ad2, rowp, srcs, d_out, flags, N);
}